// Round 6
// baseline (321.242 us; speedup 1.0000x reference)
//
#include <hip/hip_runtime.h>
#include <hip/hip_bf16.h>

// LinearCrossAttention fused pipeline for MI355X (gfx950).
// Algebra: (1) conv1x1 commutes with bilinear resize -> K/V convs at 32x32.
//          (2) y = f_geo + bo + (Wo*KV^T)*Q / norm  -> avoids [B,N,256] QKV.
// R6: latency-bound fix -- finer tiles (1024-block grids = 4 blocks/CU),
// smem union (<=32KB/block), single-barrier double-buffered K-loop
// (stage(t+1) issued before compute(t)), bf16 KV partials, vec kvred.

#define B_ 8
#define C_ 256
#define N_ 4096
#define NS_ 1024
#define KVCH 32

typedef unsigned short u16;
using bf16x8 = __attribute__((ext_vector_type(8))) short;
using f32x4 = __attribute__((ext_vector_type(4))) float;

__device__ inline u16 f2bf(float f) {
  unsigned u = __builtin_bit_cast(unsigned, f);
  unsigned r = (u + 0x7fffu + ((u >> 16) & 1u)) >> 16;
  return (u16)r;
}
__device__ inline float bf2f(u16 x) {
  return __builtin_bit_cast(float, ((unsigned)x) << 16);
}

__device__ __forceinline__ void gl_lds16(const u16* g, u16* l) {
  __builtin_amdgcn_global_load_lds((const __attribute__((address_space(1))) void*)g,
                                   (__attribute__((address_space(3))) void*)l, 16, 0, 0);
}

template<int FM, int FN>
__device__ inline void zero_acc(f32x4 (&acc)[FM][FN]) {
#pragma unroll
  for (int m = 0; m < FM; ++m)
#pragma unroll
    for (int n = 0; n < FN; ++n)
#pragma unroll
      for (int r = 0; r < 4; ++r) acc[m][n][r] = 0.f;
}

// ---- TMxTN NT GEMM: acc += A[TM][K] * B[TN][K]^T over [k0,k1), step 32 ----
// Double-buffered [R][32] linear LDS via global_load_lds; ONE barrier/iter:
//   stage(buf0); bar; { stage(buf^1,t+1); ds_read+MFMA(buf); bar; flip }
// Safety: writes to buf^1 at t vs reads of buf^1 at t-1 separated by t-1's
// barrier; reads at t vs stage at t-1 separated by same barrier (vmcnt drain).
template<int TM, int TN>
__device__ inline void gemm_nt(const u16* __restrict__ At, const u16* __restrict__ Bt,
                               int lda, int ldb, int k0, int k1,
                               u16* __restrict__ lds, f32x4 (&acc)[TM/32][TN/32])
{
  const int t = threadIdx.x;
  const int lane = t & 63, wave = t >> 6;
  const int wr = wave >> 1, wc = wave & 1;
  const int lr = lane & 15, lg = lane >> 4;
  const int sr = t >> 2, skv = (t & 3) * 8;
  constexpr int BUF = (TM + TN) * 32;
  const u16* gA = At + (size_t)sr * lda + skv;
  const u16* gB = Bt + (size_t)sr * ldb + skv;
  auto stage = [&](int buf, int k) {
    u16* Ab = lds + buf * BUF;
    u16* Bb = Ab + TM * 32;
#pragma unroll
    for (int i = 0; i < TM / 64; ++i)
      gl_lds16(gA + (size_t)i * 64 * lda + k, Ab + i * 2048 + wave * 512);
#pragma unroll
    for (int i = 0; i < TN / 64; ++i)
      gl_lds16(gB + (size_t)i * 64 * ldb + k, Bb + i * 2048 + wave * 512);
  };
  stage(0, k0);
  __syncthreads();
  const int nt = (k1 - k0) >> 5;
  int cur = 0;
  for (int it = 0; it < nt; ++it) {
    if (it + 1 < nt) stage(cur ^ 1, k0 + (it + 1) * 32);
    const u16* Ab = lds + cur * BUF;
    const u16* Bb = Ab + TM * 32;
    const u16* ap = Ab + (wr * (TM / 2) + lr) * 32 + lg * 8;
    const u16* bp = Bb + (wc * (TN / 2) + lr) * 32 + lg * 8;
    bf16x8 af[TM / 32], bfr[TN / 32];
#pragma unroll
    for (int i = 0; i < TM / 32; ++i) af[i] = *(const bf16x8*)(ap + i * 16 * 32);
#pragma unroll
    for (int i = 0; i < TN / 32; ++i) bfr[i] = *(const bf16x8*)(bp + i * 16 * 32);
#pragma unroll
    for (int m = 0; m < TM / 32; ++m)
#pragma unroll
      for (int n = 0; n < TN / 32; ++n)
        acc[m][n] = __builtin_amdgcn_mfma_f32_16x16x32_bf16(af[m], bfr[n], acc[m][n], 0, 0, 0);
    __syncthreads();
    cur ^= 1;
  }
}

// stage rows [q*32, q*32+32) of the TMxTN acc tile into eplds[32][TN+4]
template<int TM, int TN>
__device__ inline void ep_stage_chunk(const f32x4 (&acc)[TM/32][TN/32], float* eplds, int q,
                                      int wr, int wc, int lr, int lg)
{
#pragma unroll
  for (int m = 0; m < TM / 32; ++m) {
    int r0 = wr * (TM / 2) + m * 16;
    if (r0 >= q * 32 && r0 < q * 32 + 32) {
#pragma unroll
      for (int n = 0; n < TN / 32; ++n)
#pragma unroll
        for (int r = 0; r < 4; ++r)
          eplds[(r0 - q * 32 + lg * 4 + r) * (TN + 4) + wc * (TN / 2) + n * 16 + lr] = acc[m][n][r];
    }
  }
}

// ---- prep kernels ----
__global__ __launch_bounds__(256) void k_transpose_cast(const float* __restrict__ in,
                                                        u16* __restrict__ out, int rows, int cols)
{
  __shared__ float tile[32][33];
  int b = blockIdx.z;
  const float* src = in + (size_t)b * rows * cols;
  u16* dst = out + (size_t)b * rows * cols;
  int c0 = blockIdx.x * 32, r0 = blockIdx.y * 32;
  int tx = threadIdx.x & 31, ty = threadIdx.x >> 5;
#pragma unroll
  for (int i = 0; i < 32; i += 8)
    tile[ty + i][tx] = src[(size_t)(r0 + ty + i) * cols + (c0 + tx)];
  __syncthreads();
#pragma unroll
  for (int i = 0; i < 32; i += 8)
    dst[(size_t)(c0 + ty + i) * rows + (r0 + tx)] = f2bf(tile[tx][ty + i]);
}

__global__ __launch_bounds__(256) void k_cast4(const float* __restrict__ w0, const float* __restrict__ w1,
                                               const float* __restrict__ w2, const float* __restrict__ w3,
                                               u16* o0, u16* o1, u16* o2, u16* o3,
                                               float* __restrict__ stats, float* __restrict__ normv)
{
  int i = blockIdx.x * 256 + threadIdx.x;
  o0[i] = f2bf(w0[i]); o1[i] = f2bf(w1[i]); o2[i] = f2bf(w2[i]); o3[i] = f2bf(w3[i]);
  if (i < 16) stats[i] = 0.f;
  if (i < B_ * N_) normv[i] = 1e-6f;
}

// ---- K/V conv at 32x32 (128x128 tiles) ----
__global__ __launch_bounds__(256) void k_semconv(const u16* __restrict__ fsemT,
                                                 const u16* __restrict__ Wk, const u16* __restrict__ Wv,
                                                 const float* __restrict__ bk, const float* __restrict__ bv,
                                                 u16* __restrict__ Kpre, u16* __restrict__ Vpre)
{
  __shared__ __align__(16) char smem[32768];
  u16* glds = (u16*)smem;
  float* eplds = (float*)smem;
  int b = blockIdx.z >> 1, sel = blockIdx.z & 1;
  int m0 = blockIdx.y * 128, n0 = blockIdx.x * 128;
  const u16* A = (sel ? Wv : Wk) + (size_t)m0 * C_;
  const u16* Bm = fsemT + (size_t)b * NS_ * C_ + (size_t)n0 * C_;
  const float* bias = sel ? bv : bk;
  u16* out = (sel ? Vpre : Kpre) + (size_t)b * C_ * NS_;
  f32x4 acc[4][4];
  zero_acc(acc);
  gemm_nt<128, 128>(A, Bm, C_, C_, 0, C_, glds, acc);
  int t = threadIdx.x, lane = t & 63, wave = t >> 6;
  int wr = wave >> 1, wc = wave & 1, lr = lane & 15, lg = lane >> 4;
  for (int q = 0; q < 4; ++q) {
    ep_stage_chunk<128, 128>(acc, eplds, q, wr, wc, lr, lg);
    __syncthreads();
#pragma unroll
    for (int p = 0; p < 4; ++p) {
      int rloc = p * 8 + (t >> 5), cloc = (t & 31) * 4;
      int row = m0 + q * 32 + rloc;
      float4 a = *(const float4*)&eplds[rloc * 132 + cloc];
      float bi = bias[row];
      ushort4 o;
      o.x = f2bf(a.x + bi); o.y = f2bf(a.y + bi); o.z = f2bf(a.z + bi); o.w = f2bf(a.w + bi);
      *(ushort4*)&out[(size_t)row * NS_ + n0 + cloc] = o;
    }
    __syncthreads();
  }
}

// ---- bilinear 2x upsample + phi on K; fused Ksum ----
__global__ __launch_bounds__(256) void k_resize(const u16* __restrict__ Kpre, const u16* __restrict__ Vpre,
                                                u16* __restrict__ Kbf, u16* __restrict__ Vbf,
                                                float* __restrict__ Ksum)
{
  int sel = blockIdx.y;
  const u16* src = (sel ? Vpre : Kpre) + (size_t)blockIdx.x * NS_;
  u16* dst = (sel ? Vbf : Kbf) + (size_t)blockIdx.x * N_;
  float s = 0.f;
  for (int i = threadIdx.x; i < N_; i += 256) {
    int yy = i >> 6, xx = i & 63;
    int yh = yy >> 1, xh = xx >> 1;
    int ys0, ys1, xs0, xs1; float wy0, wy1, wx0, wx1;
    if (yy & 1) { ys0 = yh; ys1 = yh < 31 ? yh + 1 : 31; wy0 = 0.75f; wy1 = 0.25f; }
    else        { ys0 = yh > 0 ? yh - 1 : 0; ys1 = yh;   wy0 = 0.25f; wy1 = 0.75f; }
    if (xx & 1) { xs0 = xh; xs1 = xh < 31 ? xh + 1 : 31; wx0 = 0.75f; wx1 = 0.25f; }
    else        { xs0 = xh > 0 ? xh - 1 : 0; xs1 = xh;   wx0 = 0.25f; wx1 = 0.75f; }
    float r0 = wx0 * bf2f(src[ys0 * 32 + xs0]) + wx1 * bf2f(src[ys0 * 32 + xs1]);
    float r1 = wx0 * bf2f(src[ys1 * 32 + xs0]) + wx1 * bf2f(src[ys1 * 32 + xs1]);
    float v = wy0 * r0 + wy1 * r1;
    if (!sel) { v = v > 0.f ? v + 1.f : __expf(v); s += v; }
    dst[i] = f2bf(v);
  }
  if (!sel) {
    __shared__ float red[256];
    red[threadIdx.x] = s; __syncthreads();
    for (int off = 128; off > 0; off >>= 1) {
      if (threadIdx.x < off) red[threadIdx.x] += red[threadIdx.x + off];
      __syncthreads();
    }
    if (threadIdx.x == 0) Ksum[blockIdx.x] = red[0];
  }
}

// ---- KV split-K partials (bf16), KVCH chunks of N_/KVCH ----
__global__ __launch_bounds__(256) void k_kv(const u16* __restrict__ Kbf, const u16* __restrict__ Vbf,
                                            u16* __restrict__ KVpart)
{
  __shared__ __align__(16) char smem[32768];
  u16* glds = (u16*)smem;
  float* eplds = (float*)smem;
  int tn = blockIdx.x, tm = blockIdx.y;
  int b = blockIdx.z >> 5, ch = blockIdx.z & 31;
  const int kspan = N_ / KVCH;  // 128
  const u16* A = Kbf + (size_t)b * C_ * N_ + (size_t)tm * 128 * N_;
  const u16* Bm = Vbf + (size_t)b * C_ * N_ + (size_t)tn * 128 * N_;
  f32x4 acc[4][4];
  zero_acc(acc);
  gemm_nt<128, 128>(A, Bm, N_, N_, ch * kspan, ch * kspan + kspan, glds, acc);
  u16* out = KVpart + ((size_t)(b * KVCH + ch) * 4 + tm * 2 + tn) * (128 * 128);
  int t = threadIdx.x, lane = t & 63, wave = t >> 6;
  int wr = wave >> 1, wc = wave & 1, lr = lane & 15, lg = lane >> 4;
  for (int q = 0; q < 4; ++q) {
    ep_stage_chunk<128, 128>(acc, eplds, q, wr, wc, lr, lg);
    __syncthreads();
#pragma unroll
    for (int p = 0; p < 4; ++p) {
      int rloc = p * 8 + (t >> 5), cloc = (t & 31) * 4;
      float4 a = *(const float4*)&eplds[rloc * 132 + cloc];
      ushort4 o;
      o.x = f2bf(a.x); o.y = f2bf(a.y); o.z = f2bf(a.z); o.w = f2bf(a.w);
      *(ushort4*)&out[(size_t)(q * 32 + rloc) * 128 + cloc] = o;
    }
    __syncthreads();
  }
}

// ---- reduce bf16 partials: KVbf[c][d] = sum_ch KVpart ----
__global__ __launch_bounds__(256) void k_kvred(const u16* __restrict__ KVpart, u16* __restrict__ KVbf)
{
  int q = blockIdx.x * 256 + threadIdx.x;  // quad index, B*C*C/4 = 131072
  int b = q >> 14;
  int rem = q & 16383;
  int c = rem >> 6;
  int d0 = (rem & 63) * 4;
  int tile = ((c >> 7) << 1) + (d0 >> 7);
  int loc = (c & 127) * 128 + (d0 & 127);
  const u16* base = KVpart + (size_t)b * KVCH * 4 * 16384 + (size_t)tile * 16384 + loc;
  float s0 = 0.f, s1 = 0.f, s2 = 0.f, s3 = 0.f;
#pragma unroll
  for (int ch = 0; ch < KVCH; ++ch) {
    ushort4 v = *(const ushort4*)(base + (size_t)ch * 4 * 16384);
    s0 += bf2f(v.x); s1 += bf2f(v.y); s2 += bf2f(v.z); s3 += bf2f(v.w);
  }
  ushort4 o;
  o.x = f2bf(s0); o.y = f2bf(s1); o.z = f2bf(s2); o.w = f2bf(s3);
  *(ushort4*)&KVbf[(size_t)q * 4] = o;
}

// ---- M[o][c] = sum_d Wo[o][d] * KV[c][d] ----
__global__ __launch_bounds__(256) void k_mgemm(const u16* __restrict__ Wo, const u16* __restrict__ KVbf,
                                               u16* __restrict__ Mbf)
{
  __shared__ __align__(16) char smem[32768];
  u16* glds = (u16*)smem;
  float* eplds = (float*)smem;
  int tn = blockIdx.x, tm = blockIdx.y, b = blockIdx.z;
  const u16* A = Wo + (size_t)tm * 128 * C_;
  const u16* Bm = KVbf + (size_t)b * C_ * C_ + (size_t)tn * 128 * C_;
  f32x4 acc[4][4];
  zero_acc(acc);
  gemm_nt<128, 128>(A, Bm, C_, C_, 0, C_, glds, acc);
  u16* out = Mbf + (size_t)b * C_ * C_;
  int t = threadIdx.x, lane = t & 63, wave = t >> 6;
  int wr = wave >> 1, wc = wave & 1, lr = lane & 15, lg = lane >> 4;
  for (int q = 0; q < 4; ++q) {
    ep_stage_chunk<128, 128>(acc, eplds, q, wr, wc, lr, lg);
    __syncthreads();
#pragma unroll
    for (int p = 0; p < 4; ++p) {
      int rloc = p * 8 + (t >> 5), cloc = (t & 31) * 4;
      int row = tm * 128 + q * 32 + rloc;
      float4 a = *(const float4*)&eplds[rloc * 132 + cloc];
      ushort4 o;
      o.x = f2bf(a.x); o.y = f2bf(a.y); o.z = f2bf(a.z); o.w = f2bf(a.w);
      *(ushort4*)&out[(size_t)row * C_ + tn * 128 + cloc] = o;
    }
    __syncthreads();
  }
}

// ---- Qt[n][c] = phi(fgeoT*Wq + bq); fused norm partials. 64n x 128c tiles ----
__global__ __launch_bounds__(256) void k_qgemm(const u16* __restrict__ fgeoT, const u16* __restrict__ Wq,
                                               const float* __restrict__ bq, const float* __restrict__ Ksum,
                                               u16* __restrict__ Qt, float* __restrict__ normv)
{
  __shared__ __align__(16) char smem[24576];
  u16* glds = (u16*)smem;
  float* eplds = (float*)smem;
  int tc = blockIdx.x, tn = blockIdx.y, b = blockIdx.z;
  const u16* A = fgeoT + (size_t)b * N_ * C_ + (size_t)tn * 64 * C_;
  const u16* Bm = Wq + (size_t)tc * 128 * C_;
  f32x4 acc[2][4];
  zero_acc(acc);
  gemm_nt<64, 128>(A, Bm, C_, C_, 0, C_, glds, acc);
  u16* out = Qt + (size_t)b * N_ * C_;
  float* nb = normv + (size_t)b * N_;
  int t = threadIdx.x, lane = t & 63, wave = t >> 6;
  int wr = wave >> 1, wc = wave & 1, lr = lane & 15, lg = lane >> 4;
  for (int q = 0; q < 2; ++q) {
    ep_stage_chunk<64, 128>(acc, eplds, q, wr, wc, lr, lg);
    __syncthreads();
#pragma unroll
    for (int p = 0; p < 4; ++p) {
      int rloc = p * 8 + (t >> 5), cloc = (t & 31) * 4;
      int row = tn * 64 + q * 32 + rloc;   // n index
      int col = tc * 128 + cloc;           // c index
      float4 a = *(const float4*)&eplds[rloc * 132 + cloc];
      float4 bqv = *(const float4*)&bq[col];
      float4 ks = *(const float4*)&Ksum[b * C_ + col];
      float v0 = a.x + bqv.x; v0 = v0 > 0.f ? v0 + 1.f : __expf(v0);
      float v1 = a.y + bqv.y; v1 = v1 > 0.f ? v1 + 1.f : __expf(v1);
      float v2 = a.z + bqv.z; v2 = v2 > 0.f ? v2 + 1.f : __expf(v2);
      float v3 = a.w + bqv.w; v3 = v3 > 0.f ? v3 + 1.f : __expf(v3);
      ushort4 o;
      o.x = f2bf(v0); o.y = f2bf(v1); o.z = f2bf(v2); o.w = f2bf(v3);
      *(ushort4*)&out[(size_t)row * C_ + col] = o;
      float pv = v0 * ks.x + v1 * ks.y + v2 * ks.z + v3 * ks.w;
      pv += __shfl_xor(pv, 1); pv += __shfl_xor(pv, 2);
      pv += __shfl_xor(pv, 4); pv += __shfl_xor(pv, 8); pv += __shfl_xor(pv, 16);
      if ((t & 31) == 0) atomicAdd(&nb[row], pv);
    }
    __syncthreads();
  }
}

// ---- y = f_geo + bo + (M*Q)/norm ; GN partial stats. 128o x 64n tiles ----
__global__ __launch_bounds__(256) void k_final(const u16* __restrict__ Mbf, const u16* __restrict__ Qt,
                                               const float* __restrict__ fgeo, const float* __restrict__ bo,
                                               const float* __restrict__ normv,
                                               float* __restrict__ y, float* __restrict__ stats)
{
  __shared__ __align__(16) char smem[24576];
  u16* glds = (u16*)smem;
  float* eplds = (float*)smem;
  int tn = blockIdx.x, tm = blockIdx.y, b = blockIdx.z;
  const u16* A = Mbf + (size_t)b * C_ * C_ + (size_t)tm * 128 * C_;
  const u16* Bm = Qt + (size_t)b * N_ * C_ + (size_t)tn * 64 * C_;
  f32x4 acc[4][2];
  zero_acc(acc);
  gemm_nt<128, 64>(A, Bm, C_, C_, 0, C_, glds, acc);
  const float* nrm = normv + (size_t)b * N_;
  const float* fg = fgeo + (size_t)b * C_ * N_;
  float* yb = y + (size_t)b * C_ * N_;
  int t = threadIdx.x, lane = t & 63, wave = t >> 6;
  int wr = wave >> 1, wc = wave & 1, lr = lane & 15, lg = lane >> 4;
  float ssum = 0.f, ssq = 0.f;
  for (int q = 0; q < 4; ++q) {
    ep_stage_chunk<128, 64>(acc, eplds, q, wr, wc, lr, lg);
    __syncthreads();
#pragma unroll
    for (int p = 0; p < 2; ++p) {
      int rloc = p * 16 + (t >> 4), cloc = (t & 15) * 4;
      int row = tm * 128 + q * 32 + rloc;
      int col = tn * 64 + cloc;
      float4 a = *(const float4*)&eplds[rloc * 68 + cloc];
      float4 nv = *(const float4*)&nrm[col];
      float4 f = *(const float4*)&fg[(size_t)row * N_ + col];
      float bov = bo[row];
      float4 v;
      v.x = f.x + bov + a.x / nv.x;
      v.y = f.y + bov + a.y / nv.y;
      v.z = f.z + bov + a.z / nv.z;
      v.w = f.w + bov + a.w / nv.w;
      *(float4*)&yb[(size_t)row * N_ + col] = v;
      ssum += v.x + v.y + v.z + v.w;
      ssq += v.x * v.x + v.y * v.y + v.z * v.z + v.w * v.w;
    }
    __syncthreads();
  }
#pragma unroll
  for (int off = 1; off < 64; off <<= 1) {
    ssum += __shfl_xor(ssum, off);
    ssq += __shfl_xor(ssq, off);
  }
  if (lane == 0) {
    atomicAdd(&stats[b * 2], ssum);
    atomicAdd(&stats[b * 2 + 1], ssq);
  }
}

// ---- GN affine apply ----
__global__ __launch_bounds__(256) void k_gn(float* __restrict__ y, const float* __restrict__ stats,
                                            const float* __restrict__ gnw, const float* __restrict__ gnb)
{
  int idx = blockIdx.x * 256 + threadIdx.x;
  int elem = idx * 8;
  int b = elem >> 20;
  int o = (elem >> 12) & 255;
  const float cnt = (float)C_ * (float)N_;
  float mu = stats[b * 2] / cnt;
  float var = stats[b * 2 + 1] / cnt - mu * mu;
  float rs = rsqrtf(var + 1e-5f);
  float sc = gnw[o] * rs;
  float sh = gnb[o] - mu * sc;
  float4* p = reinterpret_cast<float4*>(y) + idx * 2;
  float4 v0 = p[0], v1 = p[1];
  v0.x = v0.x * sc + sh; v0.y = v0.y * sc + sh; v0.z = v0.z * sc + sh; v0.w = v0.w * sc + sh;
  v1.x = v1.x * sc + sh; v1.y = v1.y * sc + sh; v1.z = v1.z * sc + sh; v1.w = v1.w * sc + sh;
  p[0] = v0; p[1] = v1;
}

extern "C" void kernel_launch(void* const* d_in, const int* in_sizes, int n_in,
                              void* d_out, int out_size, void* d_ws, size_t ws_size,
                              hipStream_t stream)
{
  const float* f_geo = (const float*)d_in[0];
  const float* f_sem = (const float*)d_in[1];
  const float* Wq = (const float*)d_in[2];
  const float* bq = (const float*)d_in[3];
  const float* Wk = (const float*)d_in[4];
  const float* bk = (const float*)d_in[5];
  const float* Wv = (const float*)d_in[6];
  const float* bv = (const float*)d_in[7];
  const float* Wo = (const float*)d_in[8];
  const float* bo = (const float*)d_in[9];
  const float* gnw = (const float*)d_in[10];
  const float* gnb = (const float*)d_in[11];
  float* y = (float*)d_out;

  char* w = (char*)d_ws;
  auto alloc = [&](size_t bytes) { char* p = w; w += (bytes + 255) & ~(size_t)255; return p; };
  u16* fsemT = (u16*)alloc((size_t)B_ * NS_ * C_ * 2);
  u16* fgeoT = (u16*)alloc((size_t)B_ * N_ * C_ * 2);
  u16* Wqb = (u16*)alloc(65536 * 2);
  u16* Wkb = (u16*)alloc(65536 * 2);
  u16* Wvb = (u16*)alloc(65536 * 2);
  u16* Wob = (u16*)alloc(65536 * 2);
  u16* Kpre = (u16*)alloc((size_t)B_ * C_ * NS_ * 2);
  u16* Vpre = (u16*)alloc((size_t)B_ * C_ * NS_ * 2);
  u16* Kbf = (u16*)alloc((size_t)B_ * C_ * N_ * 2);
  u16* Vbf = (u16*)alloc((size_t)B_ * C_ * N_ * 2);
  float* Ksum = (float*)alloc((size_t)B_ * C_ * 4);
  u16* KVpart = (u16*)alloc((size_t)B_ * KVCH * 4 * 16384 * 2);
  u16* KVbf = (u16*)alloc((size_t)B_ * C_ * C_ * 2);
  u16* Mbf = (u16*)alloc((size_t)B_ * C_ * C_ * 2);
  u16* Qt = (u16*)alloc((size_t)B_ * N_ * C_ * 2);
  float* normv = (float*)alloc((size_t)B_ * N_ * 4);
  float* stats = (float*)alloc(256);

  k_transpose_cast<<<dim3(NS_ / 32, C_ / 32, B_), 256, 0, stream>>>(f_sem, fsemT, C_, NS_);
  k_transpose_cast<<<dim3(N_ / 32, C_ / 32, B_), 256, 0, stream>>>(f_geo, fgeoT, C_, N_);
  k_cast4<<<dim3(256), 256, 0, stream>>>(Wq, Wk, Wv, Wo, Wqb, Wkb, Wvb, Wob, stats, normv);
  k_semconv<<<dim3(8, 2, 16), 256, 0, stream>>>(fsemT, Wkb, Wvb, bk, bv, Kpre, Vpre);
  k_resize<<<dim3(B_ * C_, 2), 256, 0, stream>>>(Kpre, Vpre, Kbf, Vbf, Ksum);
  k_kv<<<dim3(2, 2, B_ * KVCH), 256, 0, stream>>>(Kbf, Vbf, KVpart);
  k_kvred<<<dim3(512), 256, 0, stream>>>(KVpart, KVbf);
  k_mgemm<<<dim3(2, 2, B_), 256, 0, stream>>>(Wob, KVbf, Mbf);
  k_qgemm<<<dim3(2, 64, B_), 256, 0, stream>>>(fgeoT, Wqb, bq, Ksum, Qt, normv);
  k_final<<<dim3(64, 2, B_), 256, 0, stream>>>(Mbf, Qt, f_geo, bo, normv, y, stats);
  k_gn<<<dim3(B_ * C_ * N_ / 8 / 256), 256, 0, stream>>>(y, stats, gnw, gnb);
}

// Round 7
// 277.238 us; speedup vs baseline: 1.1587x; 1.1587x over previous
//
#include <hip/hip_runtime.h>
#include <hip/hip_bf16.h>

// LinearCrossAttention fused pipeline for MI355X (gfx950).
// Algebra: (1) conv1x1 commutes with bilinear resize -> K/V convs at 32x32.
//          (2) y = f_geo + bo + (Wo*KV^T)*Q/norm, and Wo folds into V:
//              M[o][c] = sum_p (Wov*f_sem_r + bov)[o][p] * K[c][p], Wov=Wo*Wv.
// R7: revert K-loop to proven R5 2-barrier m97 structure (R6 prefetch variant
// forced vmcnt drain before ds_read -> 2x regression). New k_fuse merges
// qgemm+norm+final: Q lives only in LDS, norm computed in-block.

#define B_ 8
#define C_ 256
#define N_ 4096
#define NS_ 1024
#define KVCH 16

typedef unsigned short u16;
using bf16x8 = __attribute__((ext_vector_type(8))) short;
using f32x4 = __attribute__((ext_vector_type(4))) float;

__device__ inline u16 f2bf(float f) {
  unsigned u = __builtin_bit_cast(unsigned, f);
  unsigned r = (u + 0x7fffu + ((u >> 16) & 1u)) >> 16;
  return (u16)r;
}
__device__ inline float bf2f(u16 x) {
  return __builtin_bit_cast(float, ((unsigned)x) << 16);
}

__device__ __forceinline__ void gl_lds16(const u16* g, u16* l) {
  __builtin_amdgcn_global_load_lds((const __attribute__((address_space(1))) void*)g,
                                   (__attribute__((address_space(3))) void*)l, 16, 0, 0);
}

// ---- R5-proven 128x128 NT GEMM: stage-current; bar; compute; bar ----
__device__ inline void gemm128_nt(const u16* __restrict__ At, const u16* __restrict__ Bt,
                                  int lda, int ldb, int k0, int k1,
                                  u16* __restrict__ lds, f32x4 acc[4][4])
{
  const int t = threadIdx.x;
  const int lane = t & 63, wave = t >> 6;
  const int wr = wave >> 1, wc = wave & 1;
  const int lr = lane & 15, lg = lane >> 4;
  const int sr = t >> 2, skv = (t & 3) * 8;
  u16* Ab = lds;
  u16* Bb = lds + 128 * 32;
  const u16* gA0 = At + (size_t)sr * lda + skv;
  const u16* gA1 = At + (size_t)(sr + 64) * lda + skv;
  const u16* gB0 = Bt + (size_t)sr * ldb + skv;
  const u16* gB1 = Bt + (size_t)(sr + 64) * ldb + skv;
  u16* dA0 = Ab + wave * 512;
  u16* dA1 = Ab + 2048 + wave * 512;
  u16* dB0 = Bb + wave * 512;
  u16* dB1 = Bb + 2048 + wave * 512;
  const u16* ap = Ab + (wr * 64 + lr) * 32 + lg * 8;
  const u16* bp = Bb + (wc * 64 + lr) * 32 + lg * 8;
  for (int k = k0; k < k1; k += 32) {
    gl_lds16(gA0 + k, dA0);
    gl_lds16(gA1 + k, dA1);
    gl_lds16(gB0 + k, dB0);
    gl_lds16(gB1 + k, dB1);
    __syncthreads();
    bf16x8 af[4], bfr[4];
#pragma unroll
    for (int i = 0; i < 4; ++i) af[i] = *reinterpret_cast<const bf16x8*>(ap + i * 16 * 32);
#pragma unroll
    for (int i = 0; i < 4; ++i) bfr[i] = *reinterpret_cast<const bf16x8*>(bp + i * 16 * 32);
#pragma unroll
    for (int m = 0; m < 4; ++m)
#pragma unroll
      for (int n = 0; n < 4; ++n)
        acc[m][n] = __builtin_amdgcn_mfma_f32_16x16x32_bf16(af[m], bfr[n], acc[m][n], 0, 0, 0);
    __syncthreads();
  }
}

__device__ inline void zero_acc4(f32x4 acc[4][4]) {
#pragma unroll
  for (int m = 0; m < 4; ++m)
#pragma unroll
    for (int n = 0; n < 4; ++n)
#pragma unroll
      for (int r = 0; r < 4; ++r) acc[m][n][r] = 0.f;
}

__device__ inline void ep_stage_half(const f32x4 acc[4][4], float* eplds, int h,
                                     int wr, int wc, int lr, int lg)
{
  if (wr == h) {
#pragma unroll
    for (int m = 0; m < 4; ++m)
#pragma unroll
      for (int n = 0; n < 4; ++n)
#pragma unroll
        for (int r = 0; r < 4; ++r)
          eplds[(m * 16 + lg * 4 + r) * 132 + wc * 64 + n * 16 + lr] = acc[m][n][r];
  }
}

// ---- prep ----
__global__ __launch_bounds__(256) void k_transpose_cast(const float* __restrict__ in,
                                                        u16* __restrict__ out, int rows, int cols)
{
  __shared__ float tile[32][33];
  int b = blockIdx.z;
  const float* src = in + (size_t)b * rows * cols;
  u16* dst = out + (size_t)b * rows * cols;
  int c0 = blockIdx.x * 32, r0 = blockIdx.y * 32;
  int tx = threadIdx.x & 31, ty = threadIdx.x >> 5;
#pragma unroll
  for (int i = 0; i < 32; i += 8)
    tile[ty + i][tx] = src[(size_t)(r0 + ty + i) * cols + (c0 + tx)];
  __syncthreads();
#pragma unroll
  for (int i = 0; i < 32; i += 8)
    dst[(size_t)(c0 + ty + i) * rows + (r0 + tx)] = f2bf(tile[tx][ty + i]);
}

// cast Wq,Wk,Wo -> bf16; block 255 computes bov = Wo*bv; zero stats
__global__ __launch_bounds__(256) void k_cast3(const float* __restrict__ wq, const float* __restrict__ wk,
                                               const float* __restrict__ wo,
                                               u16* oq, u16* ok, u16* oo,
                                               const float* __restrict__ bv, float* __restrict__ bov,
                                               float* __restrict__ stats)
{
  int i = blockIdx.x * 256 + threadIdx.x;
  oq[i] = f2bf(wq[i]); ok[i] = f2bf(wk[i]); oo[i] = f2bf(wo[i]);
  if (i < 16) stats[i] = 0.f;
  if (blockIdx.x == 255) {
    int o = threadIdx.x;
    float s = 0.f;
    for (int d = 0; d < C_; ++d) s += wo[o * C_ + d] * bv[d];
    bov[o] = s;
  }
}

// ---- Wov[o][c] = sum_d Wo[o][d] * Wv[d][c] (B = WvT[c][d]) ----
__global__ __launch_bounds__(256) void k_wov(const u16* __restrict__ Wob, const u16* __restrict__ WvT,
                                             u16* __restrict__ Wov)
{
  __shared__ u16 glds[2 * 128 * 32];
  __shared__ float eplds[64 * 132];
  int tn = blockIdx.x, tm = blockIdx.y;
  const u16* A = Wob + (size_t)tm * 128 * C_;
  const u16* Bm = WvT + (size_t)tn * 128 * C_;
  f32x4 acc[4][4];
  zero_acc4(acc);
  gemm128_nt(A, Bm, C_, C_, 0, C_, glds, acc);
  int t = threadIdx.x, lane = t & 63, wave = t >> 6;
  int wr = wave >> 1, wc = wave & 1, lr = lane & 15, lg = lane >> 4;
  for (int h = 0; h < 2; ++h) {
    __syncthreads();
    ep_stage_half(acc, eplds, h, wr, wc, lr, lg);
    __syncthreads();
#pragma unroll
    for (int p = 0; p < 4; ++p) {
      int rloc = p * 8 + (t >> 5), cloc = (t & 31) * 4;
      int row = tm * 128 + h * 64 + rloc;
      float4 a = *(const float4*)&eplds[rloc * 132 + cloc];
      ushort4 o;
      o.x = f2bf(a.x); o.y = f2bf(a.y); o.z = f2bf(a.z); o.w = f2bf(a.w);
      *(ushort4*)&Wov[(size_t)row * C_ + tn * 128 + cloc] = o;
    }
  }
}

// ---- K / V2 conv at 32x32: sel 0 -> Wk,bk -> Kpre ; sel 1 -> Wov,bov -> V2pre ----
__global__ __launch_bounds__(256) void k_semconv(const u16* __restrict__ fsemT,
                                                 const u16* __restrict__ Wk, const u16* __restrict__ Wov,
                                                 const float* __restrict__ bk, const float* __restrict__ bov,
                                                 u16* __restrict__ Kpre, u16* __restrict__ V2pre)
{
  __shared__ u16 glds[2 * 128 * 32];
  __shared__ float eplds[64 * 132];
  int b = blockIdx.z >> 1, sel = blockIdx.z & 1;
  int m0 = blockIdx.y * 128, n0 = blockIdx.x * 128;
  const u16* A = (sel ? Wov : Wk) + (size_t)m0 * C_;
  const u16* Bm = fsemT + (size_t)b * NS_ * C_ + (size_t)n0 * C_;
  const float* bias = sel ? bov : bk;
  u16* out = (sel ? V2pre : Kpre) + (size_t)b * C_ * NS_;
  f32x4 acc[4][4];
  zero_acc4(acc);
  gemm128_nt(A, Bm, C_, C_, 0, C_, glds, acc);
  int t = threadIdx.x, lane = t & 63, wave = t >> 6;
  int wr = wave >> 1, wc = wave & 1, lr = lane & 15, lg = lane >> 4;
  for (int h = 0; h < 2; ++h) {
    __syncthreads();
    ep_stage_half(acc, eplds, h, wr, wc, lr, lg);
    __syncthreads();
#pragma unroll
    for (int p = 0; p < 4; ++p) {
      int rloc = p * 8 + (t >> 5), cloc = (t & 31) * 4;
      int row = m0 + h * 64 + rloc;
      float4 a = *(const float4*)&eplds[rloc * 132 + cloc];
      float bi = bias[row];
      ushort4 o;
      o.x = f2bf(a.x + bi); o.y = f2bf(a.y + bi); o.z = f2bf(a.z + bi); o.w = f2bf(a.w + bi);
      *(ushort4*)&out[(size_t)row * NS_ + n0 + cloc] = o;
    }
  }
}

// ---- bilinear 2x upsample; phi+Ksum on K planes ----
__global__ __launch_bounds__(256) void k_resize(const u16* __restrict__ Kpre, const u16* __restrict__ V2pre,
                                                u16* __restrict__ Kbf, u16* __restrict__ V2bf,
                                                float* __restrict__ Ksum)
{
  int sel = blockIdx.y;
  const u16* src = (sel ? V2pre : Kpre) + (size_t)blockIdx.x * NS_;
  u16* dst = (sel ? V2bf : Kbf) + (size_t)blockIdx.x * N_;
  float s = 0.f;
  for (int i = threadIdx.x; i < N_; i += 256) {
    int yy = i >> 6, xx = i & 63;
    int yh = yy >> 1, xh = xx >> 1;
    int ys0, ys1, xs0, xs1; float wy0, wy1, wx0, wx1;
    if (yy & 1) { ys0 = yh; ys1 = yh < 31 ? yh + 1 : 31; wy0 = 0.75f; wy1 = 0.25f; }
    else        { ys0 = yh > 0 ? yh - 1 : 0; ys1 = yh;   wy0 = 0.25f; wy1 = 0.75f; }
    if (xx & 1) { xs0 = xh; xs1 = xh < 31 ? xh + 1 : 31; wx0 = 0.75f; wx1 = 0.25f; }
    else        { xs0 = xh > 0 ? xh - 1 : 0; xs1 = xh;   wx0 = 0.25f; wx1 = 0.75f; }
    float r0 = wx0 * bf2f(src[ys0 * 32 + xs0]) + wx1 * bf2f(src[ys0 * 32 + xs1]);
    float r1 = wx0 * bf2f(src[ys1 * 32 + xs0]) + wx1 * bf2f(src[ys1 * 32 + xs1]);
    float v = wy0 * r0 + wy1 * r1;
    if (!sel) { v = v > 0.f ? v + 1.f : __expf(v); s += v; }
    dst[i] = f2bf(v);
  }
  if (!sel) {
    __shared__ float red[256];
    red[threadIdx.x] = s; __syncthreads();
    for (int off = 128; off > 0; off >>= 1) {
      if (threadIdx.x < off) red[threadIdx.x] += red[threadIdx.x + off];
      __syncthreads();
    }
    if (threadIdx.x == 0) Ksum[blockIdx.x] = red[0];
  }
}

// ---- M split-K partials: Mpart[o][c] chunk = sum_{p chunk} V2[o][p] K[c][p] ----
__global__ __launch_bounds__(256) void k_kv(const u16* __restrict__ V2bf, const u16* __restrict__ Kbf,
                                            float* __restrict__ Mpart)
{
  __shared__ u16 glds[2 * 128 * 32];
  __shared__ float eplds[64 * 132];
  int tn = blockIdx.x, tm = blockIdx.y;
  int b = blockIdx.z >> 4, ch = blockIdx.z & 15;
  const int kspan = N_ / KVCH;  // 256
  const u16* A = V2bf + (size_t)b * C_ * N_ + (size_t)tm * 128 * N_;
  const u16* Bm = Kbf + (size_t)b * C_ * N_ + (size_t)tn * 128 * N_;
  f32x4 acc[4][4];
  zero_acc4(acc);
  gemm128_nt(A, Bm, N_, N_, ch * kspan, ch * kspan + kspan, glds, acc);
  float* out = Mpart + ((size_t)(b * KVCH + ch) * 4 + tm * 2 + tn) * (128 * 128);
  int t = threadIdx.x, lane = t & 63, wave = t >> 6;
  int wr = wave >> 1, wc = wave & 1, lr = lane & 15, lg = lane >> 4;
  for (int h = 0; h < 2; ++h) {
    __syncthreads();
    ep_stage_half(acc, eplds, h, wr, wc, lr, lg);
    __syncthreads();
#pragma unroll
    for (int p = 0; p < 4; ++p) {
      int rloc = p * 8 + (t >> 5), cloc = (t & 31) * 4;
      float4 a = *(const float4*)&eplds[rloc * 132 + cloc];
      *(float4*)&out[(size_t)(h * 64 + rloc) * 128 + cloc] = a;
    }
    __syncthreads();
  }
}

// ---- reduce partials -> Mbf[o][c] bf16 ----
__global__ __launch_bounds__(256) void k_kvred(const float* __restrict__ Mpart, u16* __restrict__ Mbf)
{
  int idx = blockIdx.x * 256 + threadIdx.x;  // B*C*C = 524288
  int b = idx >> 16, cd = idx & 65535;
  int o = cd >> 8, c = cd & 255;
  int tile = ((o >> 7) << 1) + (c >> 7);
  int loc = (o & 127) * 128 + (c & 127);
  float s = 0.f;
#pragma unroll
  for (int ch = 0; ch < KVCH; ++ch)
    s += Mpart[((size_t)(b * KVCH + ch) * 4 + tile) * 16384 + loc];
  Mbf[idx] = f2bf(s);
}

// ---- MEGA-FUSE: per (64-n-tile, b): Q=phi(fgeoT*Wq+bq) -> LDS; norm in-block;
//      y = f_geo + bo + (M*Q^T)/norm ; GN stats. Qt/normv never touch HBM. ----
__global__ __launch_bounds__(256) void k_fuse(const u16* __restrict__ fgeoT, const u16* __restrict__ Wqb,
                                              const float* __restrict__ bq, const float* __restrict__ Ksum,
                                              const u16* __restrict__ Mbf,
                                              const float* __restrict__ fgeo, const float* __restrict__ bo,
                                              float* __restrict__ y, float* __restrict__ stats)
{
  __shared__ u16 Qlds[64 * 264];    // [64 n][264 c-pad] bf16, rows 528B (bank-safe)
  __shared__ float normLds[64];
  __shared__ u16 stage[4096];       // 8KB staging (ph1: A@0 B@2048; ph2: M[128][32])
  __shared__ float eplds[32 * 68];  // epilogue coalescing
  const int t = threadIdx.x, lane = t & 63, wave = t >> 6;
  const int wr = wave >> 1, wc = wave & 1;
  const int lr = lane & 15, lg = lane >> 4;
  const int sr = t >> 2, skv = (t & 3) * 8;
  const int n0 = blockIdx.x * 64, b = blockIdx.y;
  if (t < 64) normLds[t] = 1e-6f;

  // ---- phase 1: Q chunks [64n][64c], cc = 0..3 ----
  const u16* gA1 = fgeoT + (size_t)b * N_ * C_ + (size_t)(n0 + sr) * C_ + skv;
  for (int cc = 0; cc < 4; ++cc) {
    f32x4 a1[2][2];
#pragma unroll
    for (int m = 0; m < 2; ++m)
#pragma unroll
      for (int n = 0; n < 2; ++n)
#pragma unroll
        for (int r = 0; r < 4; ++r) a1[m][n][r] = 0.f;
    const u16* gB1 = Wqb + (size_t)(cc * 64 + sr) * C_ + skv;
    for (int k = 0; k < C_; k += 32) {
      gl_lds16(gA1 + k, stage + wave * 512);
      gl_lds16(gB1 + k, stage + 2048 + wave * 512);
      __syncthreads();
      const u16* ap = stage + (wr * 32 + lr) * 32 + lg * 8;
      const u16* bp = stage + 2048 + (wc * 32 + lr) * 32 + lg * 8;
      bf16x8 af[2], bfr[2];
#pragma unroll
      for (int i = 0; i < 2; ++i) af[i] = *(const bf16x8*)(ap + i * 16 * 32);
#pragma unroll
      for (int i = 0; i < 2; ++i) bfr[i] = *(const bf16x8*)(bp + i * 16 * 32);
#pragma unroll
      for (int m = 0; m < 2; ++m)
#pragma unroll
        for (int n = 0; n < 2; ++n)
          a1[m][n] = __builtin_amdgcn_mfma_f32_16x16x32_bf16(af[m], bfr[n], a1[m][n], 0, 0, 0);
      __syncthreads();
    }
    // epilogue-1: phi, write Qlds, accumulate norm
#pragma unroll
    for (int m = 0; m < 2; ++m)
#pragma unroll
      for (int r = 0; r < 4; ++r) {
        int rown = wr * 32 + m * 16 + lg * 4 + r;  // 0..63
        float pn = 0.f;
#pragma unroll
        for (int n = 0; n < 2; ++n) {
          int colg = cc * 64 + wc * 32 + n * 16 + lr;  // 0..255
          float v = a1[m][n][r] + bq[colg];
          v = v > 0.f ? v + 1.f : __expf(v);
          Qlds[rown * 264 + colg] = f2bf(v);
          pn += v * Ksum[b * C_ + colg];
        }
        pn += __shfl_xor(pn, 1); pn += __shfl_xor(pn, 2);
        pn += __shfl_xor(pn, 4); pn += __shfl_xor(pn, 8);
        if (lr == 0) atomicAdd(&normLds[rown], pn);
      }
  }

  // ---- phase 2: y chunks [128o][64n], oh = 0,1 ----
  const float* fg = fgeo + (size_t)b * C_ * N_;
  float* yb = y + (size_t)b * C_ * N_;
  float ssum = 0.f, ssq = 0.f;
  for (int oh = 0; oh < 2; ++oh) {
    f32x4 a2[4][2];
#pragma unroll
    for (int m = 0; m < 4; ++m)
#pragma unroll
      for (int n = 0; n < 2; ++n)
#pragma unroll
        for (int r = 0; r < 4; ++r) a2[m][n][r] = 0.f;
    const u16* gM = Mbf + (size_t)b * C_ * C_ + (size_t)(oh * 128 + sr) * C_ + skv;
    for (int k = 0; k < C_; k += 32) {
      gl_lds16(gM + k, stage + wave * 512);
      gl_lds16(gM + (size_t)64 * C_ + k, stage + 2048 + wave * 512);
      __syncthreads();
      const u16* ap = stage + (wr * 64 + lr) * 32 + lg * 8;
      bf16x8 af[4], bfr[2];
#pragma unroll
      for (int i = 0; i < 4; ++i) af[i] = *(const bf16x8*)(ap + i * 16 * 32);
#pragma unroll
      for (int i = 0; i < 2; ++i)
        bfr[i] = *(const bf16x8*)&Qlds[(wc * 32 + i * 16 + lr) * 264 + k + lg * 8];
#pragma unroll
      for (int m = 0; m < 4; ++m)
#pragma unroll
        for (int n = 0; n < 2; ++n)
          a2[m][n] = __builtin_amdgcn_mfma_f32_16x16x32_bf16(af[m], bfr[n], a2[m][n], 0, 0, 0);
      __syncthreads();
    }
    // epilogue-2: 4 chunks of 32 o-rows
    for (int q = 0; q < 4; ++q) {
      __syncthreads();
      if (wr == (q >> 1)) {
        int m0 = (q & 1) * 2;
#pragma unroll
        for (int mm = 0; mm < 2; ++mm)
#pragma unroll
          for (int n = 0; n < 2; ++n)
#pragma unroll
            for (int r = 0; r < 4; ++r)
              eplds[(mm * 16 + lg * 4 + r) * 68 + wc * 32 + n * 16 + lr] = a2[m0 + mm][n][r];
      }
      __syncthreads();
#pragma unroll
      for (int p = 0; p < 2; ++p) {
        int rloc = p * 16 + (t >> 4), cloc = (t & 15) * 4;
        int o = oh * 128 + q * 32 + rloc;
        float4 a = *(const float4*)&eplds[rloc * 68 + cloc];
        float4 nv = *(const float4*)&normLds[cloc];
        float4 f = *(const float4*)&fg[(size_t)o * N_ + n0 + cloc];
        float bov = bo[o];
        float4 v;
        v.x = f.x + bov + a.x / nv.x;
        v.y = f.y + bov + a.y / nv.y;
        v.z = f.z + bov + a.z / nv.z;
        v.w = f.w + bov + a.w / nv.w;
        *(float4*)&yb[(size_t)o * N_ + n0 + cloc] = v;
        ssum += v.x + v.y + v.z + v.w;
        ssq += v.x * v.x + v.y * v.y + v.z * v.z + v.w * v.w;
      }
    }
  }
#pragma unroll
  for (int off = 1; off < 64; off <<= 1) {
    ssum += __shfl_xor(ssum, off);
    ssq += __shfl_xor(ssq, off);
  }
  if (lane == 0) {
    atomicAdd(&stats[b * 2], ssum);
    atomicAdd(&stats[b * 2 + 1], ssq);
  }
}

// ---- GN affine apply ----
__global__ __launch_bounds__(256) void k_gn(float* __restrict__ y, const float* __restrict__ stats,
                                            const float* __restrict__ gnw, const float* __restrict__ gnb)
{
  int idx = blockIdx.x * 256 + threadIdx.x;
  int elem = idx * 8;
  int b = elem >> 20;
  int o = (elem >> 12) & 255;
  const float cnt = (float)C_ * (float)N_;
  float mu = stats[b * 2] / cnt;
  float var = stats[b * 2 + 1] / cnt - mu * mu;
  float rs = rsqrtf(var + 1e-5f);
  float sc = gnw[o] * rs;
  float sh = gnb[o] - mu * sc;
  float4* p = reinterpret_cast<float4*>(y) + idx * 2;
  float4 v0 = p[0], v1 = p[1];
  v0.x = v0.x * sc + sh; v0.y = v0.y * sc + sh; v0.z = v0.z * sc + sh; v0.w = v0.w * sc + sh;
  v1.x = v1.x * sc + sh; v1.y = v1.y * sc + sh; v1.z = v1.z * sc + sh; v1.w = v1.w * sc + sh;
  p[0] = v0; p[1] = v1;
}

extern "C" void kernel_launch(void* const* d_in, const int* in_sizes, int n_in,
                              void* d_out, int out_size, void* d_ws, size_t ws_size,
                              hipStream_t stream)
{
  const float* f_geo = (const float*)d_in[0];
  const float* f_sem = (const float*)d_in[1];
  const float* Wq = (const float*)d_in[2];
  const float* bq = (const float*)d_in[3];
  const float* Wk = (const float*)d_in[4];
  const float* bk = (const float*)d_in[5];
  const float* Wv = (const float*)d_in[6];
  const float* bv = (const float*)d_in[7];
  const float* Wo = (const float*)d_in[8];
  const float* bo = (const float*)d_in[9];
  const float* gnw = (const float*)d_in[10];
  const float* gnb = (const float*)d_in[11];
  float* y = (float*)d_out;

  char* w = (char*)d_ws;
  auto alloc = [&](size_t bytes) { char* p = w; w += (bytes + 255) & ~(size_t)255; return p; };
  u16* fsemT = (u16*)alloc((size_t)B_ * NS_ * C_ * 2);
  u16* fgeoT = (u16*)alloc((size_t)B_ * N_ * C_ * 2);
  u16* Wqb = (u16*)alloc(65536 * 2);
  u16* Wkb = (u16*)alloc(65536 * 2);
  u16* Wob = (u16*)alloc(65536 * 2);
  u16* WvT = (u16*)alloc(65536 * 2);
  u16* Wov = (u16*)alloc(65536 * 2);
  float* bov = (float*)alloc(C_ * 4);
  u16* Kpre = (u16*)alloc((size_t)B_ * C_ * NS_ * 2);
  u16* V2pre = (u16*)alloc((size_t)B_ * C_ * NS_ * 2);
  u16* Kbf = (u16*)alloc((size_t)B_ * C_ * N_ * 2);
  u16* V2bf = (u16*)alloc((size_t)B_ * C_ * N_ * 2);
  float* Ksum = (float*)alloc((size_t)B_ * C_ * 4);
  float* Mpart = (float*)alloc((size_t)B_ * KVCH * 4 * 16384 * 4);
  u16* Mbf = (u16*)alloc((size_t)B_ * C_ * C_ * 2);
  float* stats = (float*)alloc(256);

  k_transpose_cast<<<dim3(NS_ / 32, C_ / 32, B_), 256, 0, stream>>>(f_sem, fsemT, C_, NS_);
  k_transpose_cast<<<dim3(N_ / 32, C_ / 32, B_), 256, 0, stream>>>(f_geo, fgeoT, C_, N_);
  k_transpose_cast<<<dim3(C_ / 32, C_ / 32, 1), 256, 0, stream>>>(Wv, WvT, C_, C_);
  k_cast3<<<dim3(256), 256, 0, stream>>>(Wq, Wk, Wo, Wqb, Wkb, Wob, bv, bov, stats);
  k_wov<<<dim3(2, 2), 256, 0, stream>>>(Wob, WvT, Wov);
  k_semconv<<<dim3(8, 2, 16), 256, 0, stream>>>(fsemT, Wkb, Wov, bk, bov, Kpre, V2pre);
  k_resize<<<dim3(B_ * C_, 2), 256, 0, stream>>>(Kpre, V2pre, Kbf, V2bf, Ksum);
  k_kv<<<dim3(2, 2, B_ * KVCH), 256, 0, stream>>>(V2bf, Kbf, Mpart);
  k_kvred<<<dim3(2048), 256, 0, stream>>>(Mpart, Mbf);
  k_fuse<<<dim3(N_ / 64, B_), 256, 0, stream>>>(fgeoT, Wqb, bq, Ksum, Mbf, f_geo, bo, y, stats);
  k_gn<<<dim3(B_ * C_ * N_ / 8 / 256), 256, 0, stream>>>(y, stats, gnw, gnb);
}